// Round 9
// baseline (1409.229 us; speedup 1.0000x reference)
//
#include <hip/hip_runtime.h>
#include <cstdint>
#include <cstddef>

#define BB 256
#define TT 250
#define DIN 700
#define H1 256
#define H2 256
#define DOUT 20
#define BJ0 0.01f
#define BETAC 1.8f
#define DUMMY 256                 // zero row index in every padded table
#define IQSCALE 3.814697265625e-06f   // 2^-18

typedef float f32x4 __attribute__((ext_vector_type(4)));
typedef short s16x4 __attribute__((ext_vector_type(4)));
typedef short s16x2 __attribute__((ext_vector_type(2)));

// Packed-pair accumulate: v holds cols (2c | 2c+1) as (lo | hi) int16.
// v_dot2_i32_i16 does select+sign-extend+add fused (1 VALU per half).
#if __has_builtin(__builtin_amdgcn_sdot2)
__device__ __forceinline__ void acc2(int v, int& lo, int& hi) {
    s16x2 a = __builtin_bit_cast(s16x2, v);
    s16x2 selLo = {1, 0};
    s16x2 selHi = {0, 1};
    lo = __builtin_amdgcn_sdot2(a, selLo, lo, false);
    hi = __builtin_amdgcn_sdot2(a, selHi, hi, false);
}
#else
__device__ __forceinline__ void acc2(int v, int& lo, int& hi) {
    lo += (int)(short)(v & 0xffff);
    hi += v >> 16;
}
#endif

// ---------------------------------------------------------------------------
// Workspace layout (int/float offsets from ws base; all 4B units):
//   sT1  (short) [701*256 shorts] = dwords [0, 89728)      xproj table (unpacked)
//   pT11 (int)   @  89728  [257 rows x 128 packed cols]
//   pT12 (int)   @ 122624
//   pT22 (int)   @ 155520
//   w2o  (float) @ 188416  [257*20]   (row 256 = zeros)
//   Xp   (float) @ 193556  [250*256*256]
// ---------------------------------------------------------------------------
#define IOFF_P11 89728
#define IOFF_P12 122624
#define IOFF_P22 155520
#define FOFF_W2O 188416
#define FOFF_XP  193556
#define N_TRANS  283284   // 179456 + 3*32896 + 5140

__device__ __forceinline__ short q18(float w) {
    float s = w * 262144.0f;
    s = fminf(fmaxf(s, -32767.0f), 32767.0f);
    return (short)__float2int_rn(s);
}

__global__ void transpose_all_k(const float* __restrict__ w_i2h1,
                                const float* __restrict__ w_h12h1,
                                const float* __restrict__ w_h12h2,
                                const float* __restrict__ w_h22h2,
                                const float* __restrict__ w_h2o,
                                short* __restrict__ sws,
                                int* __restrict__ iws,
                                float* __restrict__ fws) {
    int i = blockIdx.x * blockDim.x + threadIdx.x;
    if (i < 179456) { int d = i >> 8, h = i & 255;
        sws[i] = q18((d < DIN) ? w_i2h1[h * DIN + d] : 0.f); return; }
    i -= 179456;
    if (i < 32896) { int j = i >> 7, c = i & 127;
        int lo = (j < H1) ? (int)q18(w_h12h1[(2 * c) * H1 + j]) : 0;
        int hi = (j < H1) ? (int)q18(w_h12h1[(2 * c + 1) * H1 + j]) : 0;
        iws[IOFF_P11 + i] = (hi << 16) | (lo & 0xffff); return; }
    i -= 32896;
    if (i < 32896) { int j = i >> 7, c = i & 127;
        int lo = (j < H1) ? (int)q18(w_h12h2[(2 * c) * H1 + j]) : 0;
        int hi = (j < H1) ? (int)q18(w_h12h2[(2 * c + 1) * H1 + j]) : 0;
        iws[IOFF_P12 + i] = (hi << 16) | (lo & 0xffff); return; }
    i -= 32896;
    if (i < 32896) { int j = i >> 7, c = i & 127;
        int lo = (j < H2) ? (int)q18(w_h22h2[(2 * c) * H2 + j]) : 0;
        int hi = (j < H2) ? (int)q18(w_h22h2[(2 * c + 1) * H2 + j]) : 0;
        iws[IOFF_P22 + i] = (hi << 16) | (lo & 0xffff); return; }
    i -= 32896;
    if (i < 5140)  { int j = i / 20, h = i % 20;
        fws[FOFF_W2O + i] = (j < H2) ? w_h2o[h * H2 + j] : 0.f; return; }
}

// ---------------------------------------------------------------------------
// xproj: unchanged from R8 (int16 table, 8-wide groups) — known good.
// ---------------------------------------------------------------------------
__global__ __launch_bounds__(256) void xproj_k(const float* __restrict__ x,
                                               const short* __restrict__ sT1,
                                               const float* __restrict__ b_h1,
                                               float* __restrict__ Xp) {
    const int lane = threadIdx.x & 63;
    const int wv   = threadIdx.x >> 6;
    const int bt   = blockIdx.x * 4 + wv;   // grid = T*B/4 = 16000
    const int b    = bt & (BB - 1);
    const int t    = bt >> 8;

    __shared__ __align__(16) int lst[4][712];

    const float* xrow = x + ((size_t)b * TT + t) * DIN;
    int cnt = 0;
    for (int c = 0; c < 11; ++c) {
        int d = c * 64 + lane;
        bool p = false;
        if (d < DIN) p = (__builtin_nontemporal_load(xrow + d) != 0.0f);
        unsigned long long m = __ballot(p ? 1 : 0);
        if (p) {
            int pos = cnt + __popcll(m & ((1ull << lane) - 1ull));
            lst[wv][pos] = d;
        }
        cnt += __popcll(m);
    }
    int cntp = (cnt + 7) & ~7;
    if (lane < cntp - cnt) lst[wv][cnt + lane] = DIN;   // zero row pad
    __syncthreads();

    const int lo = lane * 4;
    int i0 = 0, i1 = 0, i2 = 0, i3 = 0;
    int j0 = 0, j1 = 0, j2 = 0, j3 = 0;
    for (int k = 0; k < cntp; k += 8) {
        int4 ja = *(const int4*)&lst[wv][k];
        int4 jb = *(const int4*)&lst[wv][k + 4];
        s16x4 w0 = *(const s16x4*)(sT1 + ((size_t)ja.x << 8) + lo);
        s16x4 w1 = *(const s16x4*)(sT1 + ((size_t)ja.y << 8) + lo);
        s16x4 w2 = *(const s16x4*)(sT1 + ((size_t)ja.z << 8) + lo);
        s16x4 w3 = *(const s16x4*)(sT1 + ((size_t)ja.w << 8) + lo);
        s16x4 w4 = *(const s16x4*)(sT1 + ((size_t)jb.x << 8) + lo);
        s16x4 w5 = *(const s16x4*)(sT1 + ((size_t)jb.y << 8) + lo);
        s16x4 w6 = *(const s16x4*)(sT1 + ((size_t)jb.z << 8) + lo);
        s16x4 w7 = *(const s16x4*)(sT1 + ((size_t)jb.w << 8) + lo);
        i0 += (w0.x + w1.x) + (w2.x + w3.x);  j0 += (w4.x + w5.x) + (w6.x + w7.x);
        i1 += (w0.y + w1.y) + (w2.y + w3.y);  j1 += (w4.y + w5.y) + (w6.y + w7.y);
        i2 += (w0.z + w1.z) + (w2.z + w3.z);  j2 += (w4.z + w5.z) + (w6.z + w7.z);
        i3 += (w0.w + w1.w) + (w2.w + w3.w);  j3 += (w4.w + w5.w) + (w6.w + w7.w);
    }
    f32x4 acc = *(const f32x4*)(b_h1 + lo);
    acc.x += (float)(i0 + j0) * IQSCALE;
    acc.y += (float)(i1 + j1) * IQSCALE;
    acc.z += (float)(i2 + j2) * IQSCALE;
    acc.w += (float)(i3 + j3) * IQSCALE;
    __builtin_nontemporal_store(acc, (f32x4*)(Xp + ((size_t)t * BB + b) * H1 + lo));
}

// 32 packed-pair gathered rows from list L[k..k+32), column-pair c.
__device__ __forceinline__ void gath32p(const int* __restrict__ T,
                                        const int* L, int k, int c,
                                        int& lo, int& hi) {
    int idx[32];
    #pragma unroll
    for (int i = 0; i < 32; i += 4) {
        int4 a = *(const int4*)(L + k + i);
        idx[i] = a.x; idx[i + 1] = a.y; idx[i + 2] = a.z; idx[i + 3] = a.w;
    }
    int v[32];
    #pragma unroll
    for (int i = 0; i < 32; ++i) v[i] = T[(idx[i] << 7) + c];
    int l0 = 0, h0 = 0, l1 = 0, h1 = 0;
    #pragma unroll
    for (int i = 0; i < 32; i += 2) {
        acc2(v[i], l0, h0);
        acc2(v[i + 1], l1, h1);
    }
    lo += l0 + l1;
    hi += h0 + h1;
}

// 32 fp32 output-weight values from LDS table (stride DOUT), list L2.
__device__ __forceinline__ float g32o(const float* w2oL, const int* L2,
                                      int k, int t) {
    float s0 = 0.f, s1 = 0.f;
    #pragma unroll
    for (int i = 0; i < 32; i += 4) {
        int4 a = *(const int4*)(L2 + k + i);
        s0 += w2oL[a.x * DOUT + t] + w2oL[a.y * DOUT + t];
        s1 += w2oL[a.z * DOUT + t] + w2oL[a.w * DOUT + t];
    }
    return s0 + s1;
}

// ---------------------------------------------------------------------------
// rec_k: one 256-thread block per batch element.
// Gather phases use packed column-pairs: P1 maps both tables onto 256 threads
// (t<128: pT11 x lst1 ; t>=128: pT22 x lst2), P3 splits rows 2-way.
// Per-thread VMEM ~halved vs R8; 32-row groups halve drains. Results
// redistribute via LDS int psums. U-phases / ballot / list-build = R8 verbatim.
// W2o lives in LDS (no vmcnt traffic). 6 barriers/step.
// ---------------------------------------------------------------------------
__global__ __launch_bounds__(256, 1) void rec_k(
    const float* __restrict__ Xp,
    const int* __restrict__ pT11, const int* __restrict__ pT12,
    const int* __restrict__ pT22, const float* __restrict__ wT2o,
    const float* __restrict__ b_h2, const float* __restrict__ b_o,
    const float* __restrict__ tau_adp_h1, const float* __restrict__ tau_adp_h2,
    const float* __restrict__ tau_m_h1, const float* __restrict__ tau_m_h2,
    const float* __restrict__ tau_m_o,
    float* __restrict__ out) {
    const int h    = threadIdx.x;
    const int lane = h & 63;
    const int wv   = h >> 6;
    const int b    = blockIdx.x;
    const int c    = h & 127;          // packed column-pair id in gather phases

    __shared__ __align__(16) int lst1[320];
    __shared__ __align__(16) int lst2[320];
    __shared__ unsigned long long wmask[4];
    __shared__ int ps1[256], ps2[256], ps3a[256], ps3b[256];
    __shared__ float w2oL[5140];
    __shared__ float smo[DOUT];

    // stage W2o (257 x 20 fp32, row 256 zeros) into LDS
    for (int i = h; i < 5140; i += 256) w2oL[i] = wT2o[i];

    const float alpha1 = expf(-1.0f / tau_m_h1[h]);
    const float ro1    = expf(-1.0f / tau_adp_h1[h]);
    const float alpha2 = expf(-1.0f / tau_m_h2[h]);
    const float ro2    = expf(-1.0f / tau_adp_h2[h]);
    const float bh2v   = b_h2[h];
    float alpo = 0.f, bov = 0.f;
    if (h < DOUT) { alpo = expf(-1.0f / tau_m_o[h]); bov = b_o[h]; }

    float mem1 = 0.f, spk1 = 0.f, bb1v = BJ0;
    float mem2 = 0.f, spk2 = 0.f, bb2v = BJ0;
    float memo = 0.f, accs = 0.f;
    int kmaxC = 0;    // common padded list length for P1 (32-mult)
    int n1g   = 0;    // fresh lst1 padded length for P3 (64-mult)

    float xp_cur = __builtin_nontemporal_load(Xp + ((size_t)b) * H1 + h);  // t=0
    __syncthreads();   // w2oL staged

    for (int t = 0; t < TT; ++t) {
        float xp_nxt = 0.f;
        if (t + 1 < TT)
            xp_nxt = __builtin_nontemporal_load(Xp + ((size_t)(t + 1) * BB + b) * H1 + h);

        // ---- P1: packed gathers. t<128: pT11 x lst1; t>=128: pT22 x lst2.
        //      threads t<20 additionally: W2o x lst2 from LDS (lgkm path).
        const int* T = (h < 128) ? pT11 : pT22;
        const int* L = (h < 128) ? lst1 : lst2;
        int plo = 0, phi = 0;
        float ro = 0.f;
        for (int k = 0; k < kmaxC; k += 32) {
            gath32p(T, L, k, c, plo, phi);
            if (h < DOUT) ro += g32o(w2oL, lst2, k, h);
        }
        if (h < 128) { ps1[2 * c] = plo; ps1[2 * c + 1] = phi; }
        else         { ps2[2 * c] = plo; ps2[2 * c + 1] = phi; }
        __syncthreads();                               // B1a: psums ready

        // ---- U1: layer-1 update (R8 verbatim, r1 from ps1) ----
        float r1 = (float)ps1[h] * IQSCALE;
        bb1v = ro1 * bb1v + BETAC * (1.f - ro1) * spk1;
        mem1 = mem1 * alpha1 - bb1v * spk1 + (1.f - alpha1) * (xp_cur + r1);
        float ns1 = (mem1 - bb1v - BJ0) > 0.f ? 1.f : 0.f;
        spk1 = ns1;
        unsigned long long m1 = __ballot(ns1 != 0.f ? 1 : 0);
        if (lane == 0) wmask[wv] = m1;
        const bool doo = (h < DOUT) && (t > 0);
        if (doo) {
            memo = memo * alpo + (1.f - alpo) * (bov + ro);
            smo[h] = memo;
        }
        __syncthreads();                               // B1b

        // ---- P2b: rebuild lst1 (pad to 64-mult); softmax accum t-1 ----
        {
            int pos = __popcll(m1 & ((1ull << lane) - 1ull));
            int tot = 0;
            for (int w = 0; w < 4; ++w) {
                unsigned long long mw = wmask[w];
                if (w < wv) pos += __popcll(mw);
                tot += __popcll(mw);
            }
            if (ns1 != 0.f) lst1[pos] = h;
            int np = (tot + 63) & ~63;
            if (h < np - tot) lst1[tot + h] = DUMMY;
            n1g = np;
        }
        if (doo) {
            float mx = smo[0];
            for (int i = 1; i < DOUT; ++i) mx = fmaxf(mx, smo[i]);
            float s = 0.f;
            for (int i = 0; i < DOUT; ++i) s += expf(smo[i] - mx);
            accs += expf(memo - mx) / s;
        }
        __syncthreads();                               // B2: lst1 ready

        // ---- P3: packed gather pT12 over fresh lst1, rows split 2-way ----
        {
            const int half = n1g >> 1;                 // 32-mult
            int qlo = 0, qhi = 0;
            if (h < 128) for (int k = 0;    k < half; k += 32) gath32p(pT12, lst1, k, c, qlo, qhi);
            else         for (int k = half; k < n1g;  k += 32) gath32p(pT12, lst1, k, c, qlo, qhi);
            if (h < 128) { ps3a[2 * c] = qlo; ps3a[2 * c + 1] = qhi; }
            else         { ps3b[2 * c] = qlo; ps3b[2 * c + 1] = qhi; }
        }
        __syncthreads();                               // B3a: ps3 ready

        // ---- U2: layer-2 update (R8 verbatim, r from psums) ----
        float r23 = (float)(ps2[h] + ps3a[h] + ps3b[h]) * IQSCALE;
        bb2v = ro2 * bb2v + BETAC * (1.f - ro2) * spk2;
        mem2 = mem2 * alpha2 - bb2v * spk2 + (1.f - alpha2) * (bh2v + r23);
        float ns2 = (mem2 - bb2v - BJ0) > 0.f ? 1.f : 0.f;
        spk2 = ns2;
        unsigned long long m2 = __ballot(ns2 != 0.f ? 1 : 0);
        if (lane == 0) wmask[wv] = m2;
        __syncthreads();                               // B3b

        // ---- P4b: rebuild lst2; pad both lists to common kmaxC ----
        {
            int pos = __popcll(m2 & ((1ull << lane) - 1ull));
            int tot = 0;
            for (int w = 0; w < 4; ++w) {
                unsigned long long mw = wmask[w];
                if (w < wv) pos += __popcll(mw);
                tot += __popcll(mw);
            }
            if (ns2 != 0.f) lst2[pos] = h;
            int np2 = (tot + 31) & ~31;
            int nC  = n1g > np2 ? n1g : np2;
            if (h < nC - tot) lst2[tot + h] = DUMMY;
            if (h < nC - n1g) lst1[n1g + h] = DUMMY;
            kmaxC = nC;
        }
        __syncthreads();                               // B4

        xp_cur = xp_nxt;
    }

    // ---- Epilogue: output + softmax for final timestep (W2o from LDS) ----
    if (h < DOUT) {
        float ro = 0.f;
        for (int k = 0; k < kmaxC; ++k) ro += w2oL[lst2[k] * DOUT + h];
        memo = memo * alpo + (1.f - alpo) * (bov + ro);
        smo[h] = memo;
    }
    __syncthreads();
    if (h < DOUT) {
        float mx = smo[0];
        for (int i = 1; i < DOUT; ++i) mx = fmaxf(mx, smo[i]);
        float s = 0.f;
        for (int i = 0; i < DOUT; ++i) s += expf(smo[i] - mx);
        accs += expf(memo - mx) / s;
        out[b * DOUT + h] = accs;
    }
}

extern "C" void kernel_launch(void* const* d_in, const int* in_sizes, int n_in,
                              void* d_out, int out_size, void* d_ws, size_t ws_size,
                              hipStream_t stream) {
    const float* x          = (const float*)d_in[0];
    const float* w_i2h1     = (const float*)d_in[1];
    const float* w_h12h1    = (const float*)d_in[2];
    const float* w_h12h2    = (const float*)d_in[3];
    const float* w_h22h2    = (const float*)d_in[4];
    const float* w_h2o      = (const float*)d_in[5];
    const float* b_h1       = (const float*)d_in[6];
    const float* b_h2       = (const float*)d_in[7];
    const float* b_o        = (const float*)d_in[8];
    const float* tau_adp_h1 = (const float*)d_in[9];
    const float* tau_adp_h2 = (const float*)d_in[10];
    const float* tau_m_h1   = (const float*)d_in[11];
    const float* tau_m_h2   = (const float*)d_in[12];
    const float* tau_m_o    = (const float*)d_in[13];

    short* sws = (short*)d_ws;
    int*   iws = (int*)d_ws;
    float* fws = (float*)d_ws;
    const short* sT1  = sws;
    const int*   pT11 = iws + IOFF_P11;
    const int*   pT12 = iws + IOFF_P12;
    const int*   pT22 = iws + IOFF_P22;
    float* wT2o = fws + FOFF_W2O;
    float* Xp   = fws + FOFF_XP;

    transpose_all_k<<<(N_TRANS + 255) / 256, 256, 0, stream>>>(
        w_i2h1, w_h12h1, w_h12h2, w_h22h2, w_h2o, sws, iws, fws);

    xproj_k<<<(TT * BB) / 4, 256, 0, stream>>>(x, sT1, b_h1, Xp);

    rec_k<<<BB, 256, 0, stream>>>(Xp, pT11, pT12, pT22, wT2o,
                                  b_h2, b_o, tau_adp_h1, tau_adp_h2,
                                  tau_m_h1, tau_m_h2, tau_m_o,
                                  (float*)d_out);
}

// Round 10
// 1293.013 us; speedup vs baseline: 1.0899x; 1.0899x over previous
//
#include <hip/hip_runtime.h>
#include <cstdint>
#include <cstddef>

#define BB 256
#define TT 250
#define DIN 700
#define H1 256
#define H2 256
#define DOUT 20
#define BJ0 0.01f
#define BETAC 1.8f
#define DUMMY 256                 // zero row index in every padded table
#define IQSCALE 3.814697265625e-06f   // 2^-18

typedef float f32x4 __attribute__((ext_vector_type(4)));
typedef short s16x4 __attribute__((ext_vector_type(4)));

// ---------------------------------------------------------------------------
// Workspace layout. int16 tables (element offsets in shorts from ws base):
//   sT1  [701*256] @ 0        (row 700 = zeros)
//   sT11 [257*256] @ 179456   (row 256 = zeros)
//   sT12 [257*256] @ 245248
//   sT22 [257*256] @ 311040   (end: 376832 shorts = 753664 bytes)
// fp32 region (float offsets from ws base):
//   wT2o [257*20]  @ f188416  (row 256 = zeros)
//   Xp   [250*256*256] @ f193556  (byte 774224, 16B aligned)
// ---------------------------------------------------------------------------
#define SOFF_T11 179456
#define SOFF_T12 245248
#define SOFF_T22 311040
#define FOFF_W2O 188416
#define FOFF_XP  193556
#define N_TRANS  381972

__device__ __forceinline__ short q18(float w) {
    float s = w * 262144.0f;
    s = fminf(fmaxf(s, -32767.0f), 32767.0f);
    return (short)__float2int_rn(s);
}

__global__ void transpose_all_k(const float* __restrict__ w_i2h1,
                                const float* __restrict__ w_h12h1,
                                const float* __restrict__ w_h12h2,
                                const float* __restrict__ w_h22h2,
                                const float* __restrict__ w_h2o,
                                short* __restrict__ sws,
                                float* __restrict__ fws) {
    int i = blockIdx.x * blockDim.x + threadIdx.x;
    if (i < 179456) { int d = i >> 8, h = i & 255;
        sws[i] = q18((d < DIN) ? w_i2h1[h * DIN + d] : 0.f); return; }
    i -= 179456;
    if (i < 65792) { int d = i >> 8, h = i & 255;
        sws[SOFF_T11 + i] = q18((d < H1) ? w_h12h1[h * H1 + d] : 0.f); return; }
    i -= 65792;
    if (i < 65792) { int d = i >> 8, h = i & 255;
        sws[SOFF_T12 + i] = q18((d < H1) ? w_h12h2[h * H1 + d] : 0.f); return; }
    i -= 65792;
    if (i < 65792) { int d = i >> 8, h = i & 255;
        sws[SOFF_T22 + i] = q18((d < H2) ? w_h22h2[h * H2 + d] : 0.f); return; }
    i -= 65792;
    if (i < 5140)  { int j = i / 20, h = i % 20;
        fws[FOFF_W2O + i] = (j < H2) ? w_h2o[h * H2 + j] : 0.f; return; }
}

// ---------------------------------------------------------------------------
// Xp[t][b][h] = b_h1[h] + (Σ_{d active} sT1[d*256+h]) * 2^-18
// One wave per (b,t); lane covers 4 cols via short4 loads; 16-row groups.
// ---------------------------------------------------------------------------
__global__ __launch_bounds__(256, 1) void xproj_k(const float* __restrict__ x,
                                                  const short* __restrict__ sT1,
                                                  const float* __restrict__ b_h1,
                                                  float* __restrict__ Xp) {
    const int lane = threadIdx.x & 63;
    const int wv   = threadIdx.x >> 6;
    const int bt   = blockIdx.x * 4 + wv;   // grid = T*B/4 = 16000
    const int b    = bt & (BB - 1);
    const int t    = bt >> 8;

    __shared__ __align__(16) int lst[4][720];

    const float* xrow = x + ((size_t)b * TT + t) * DIN;
    int cnt = 0;
    for (int c = 0; c < 11; ++c) {
        int d = c * 64 + lane;
        bool p = false;
        if (d < DIN) p = (__builtin_nontemporal_load(xrow + d) != 0.0f);
        unsigned long long m = __ballot(p ? 1 : 0);
        if (p) {
            int pos = cnt + __popcll(m & ((1ull << lane) - 1ull));
            lst[wv][pos] = d;
        }
        cnt += __popcll(m);
    }
    int cntp = (cnt + 15) & ~15;
    if (lane < cntp - cnt) lst[wv][cnt + lane] = DIN;   // zero row pad
    __syncthreads();

    const int lo = lane * 4;
    int a0 = 0, a1 = 0, a2 = 0, a3 = 0;
    int b0 = 0, b1 = 0, b2 = 0, b3 = 0;
    for (int k = 0; k < cntp; k += 16) {
        int idx[16];
        #pragma unroll
        for (int i = 0; i < 16; i += 4) {
            int4 ja = *(const int4*)&lst[wv][k + i];
            idx[i] = ja.x; idx[i + 1] = ja.y; idx[i + 2] = ja.z; idx[i + 3] = ja.w;
        }
        s16x4 w[16];
        #pragma unroll
        for (int i = 0; i < 16; ++i)
            w[i] = *(const s16x4*)(sT1 + ((size_t)idx[i] << 8) + lo);
        #pragma unroll
        for (int i = 0; i < 16; i += 2) {
            a0 += w[i].x; a1 += w[i].y; a2 += w[i].z; a3 += w[i].w;
            b0 += w[i + 1].x; b1 += w[i + 1].y; b2 += w[i + 1].z; b3 += w[i + 1].w;
        }
    }
    f32x4 acc = *(const f32x4*)(b_h1 + lo);
    acc.x += (float)(a0 + b0) * IQSCALE;
    acc.y += (float)(a1 + b1) * IQSCALE;
    acc.z += (float)(a2 + b2) * IQSCALE;
    acc.w += (float)(a3 + b3) * IQSCALE;
    __builtin_nontemporal_store(acc, (f32x4*)(Xp + ((size_t)t * BB + b) * H1 + lo));
}

// 32 gathered int16 adds from rows L[k..k+32) of a 256-stride table, col h.
// All 32 dest values coexist before the sum tree -> wide vmcnt window.
__device__ __forceinline__ int gath32i(const short* __restrict__ W,
                                       const int* __restrict__ L, int k, int h) {
    int idx[32];
    #pragma unroll
    for (int i = 0; i < 32; i += 4) {
        int4 a = *(const int4*)(L + k + i);
        idx[i] = a.x; idx[i + 1] = a.y; idx[i + 2] = a.z; idx[i + 3] = a.w;
    }
    int v[32];
    #pragma unroll
    for (int i = 0; i < 32; ++i) v[i] = W[(idx[i] << 8) + h];
    int s0 = 0, s1 = 0, s2 = 0, s3 = 0;
    #pragma unroll
    for (int i = 0; i < 32; i += 4) {
        s0 += v[i]; s1 += v[i + 1]; s2 += v[i + 2]; s3 += v[i + 3];
    }
    return (s0 + s1) + (s2 + s3);
}

// 32 fp32 output-weight values, stride-20 table (only 20 threads execute).
__device__ __forceinline__ float gather32o(const float* __restrict__ W,
                                           const int* __restrict__ L, int k, int h) {
    float v[32];
    #pragma unroll
    for (int i = 0; i < 32; i += 4) {
        int4 a = *(const int4*)(L + k + i);
        v[i]     = W[a.x * DOUT + h];
        v[i + 1] = W[a.y * DOUT + h];
        v[i + 2] = W[a.z * DOUT + h];
        v[i + 3] = W[a.w * DOUT + h];
    }
    float s0 = 0.f, s1 = 0.f;
    #pragma unroll
    for (int i = 0; i < 32; i += 2) { s0 += v[i]; s1 += v[i + 1]; }
    return s0 + s1;
}

// ---------------------------------------------------------------------------
// Recurrent loop: EXACT R8 structure, 32-row drain groups, lists padded to
// 32-multiples. One 256-thread block per batch element (grid=256 -> 1/CU, so
// VGPR growth is free). 4 barriers per timestep.
// ---------------------------------------------------------------------------
__global__ __launch_bounds__(256, 1) void rec_k(
    const float* __restrict__ Xp,
    const short* __restrict__ sT11, const short* __restrict__ sT12,
    const short* __restrict__ sT22, const float* __restrict__ wT2o,
    const float* __restrict__ b_h2, const float* __restrict__ b_o,
    const float* __restrict__ tau_adp_h1, const float* __restrict__ tau_adp_h2,
    const float* __restrict__ tau_m_h1, const float* __restrict__ tau_m_h2,
    const float* __restrict__ tau_m_o,
    float* __restrict__ out) {
    const int h    = threadIdx.x;
    const int lane = h & 63;
    const int wv   = h >> 6;
    const int b    = blockIdx.x;

    __shared__ __align__(16) int lst1[288];
    __shared__ __align__(16) int lst2[288];
    __shared__ unsigned long long wmask[4];
    __shared__ float smo[DOUT];

    const float alpha1 = expf(-1.0f / tau_m_h1[h]);
    const float ro1    = expf(-1.0f / tau_adp_h1[h]);
    const float alpha2 = expf(-1.0f / tau_m_h2[h]);
    const float ro2    = expf(-1.0f / tau_adp_h2[h]);
    const float bh2v   = b_h2[h];
    float alpo = 0.f, bov = 0.f;
    if (h < DOUT) { alpo = expf(-1.0f / tau_m_o[h]); bov = b_o[h]; }

    float mem1 = 0.f, spk1 = 0.f, bb1v = BJ0;
    float mem2 = 0.f, spk2 = 0.f, bb2v = BJ0;
    float memo = 0.f, accs = 0.f;
    int n1p = 0, n2p = 0;

    float xp_cur = __builtin_nontemporal_load(Xp + ((size_t)b) * H1 + h);  // t=0

    for (int t = 0; t < TT; ++t) {
        float xp_nxt = 0.f;
        if (t + 1 < TT)
            xp_nxt = __builtin_nontemporal_load(Xp + ((size_t)(t + 1) * BB + b) * H1 + h);

        // ---- P1: fused gather over prev lists (sT11 | sT22 | wT2o) ----
        int ir1 = 0, ir2 = 0;
        float ro = 0.f;
        const bool doo = (h < DOUT) && (t > 0);
        const int kmax = n1p > n2p ? n1p : n2p;
        for (int k = 0; k < kmax; k += 32) {
            int s1 = 0, s2 = 0;
            float s3 = 0.f;
            if (k < n1p) s1 = gath32i(sT11, lst1, k, h);
            if (k < n2p) {
                s2 = gath32i(sT22, lst2, k, h);
                if (doo) s3 = gather32o(wT2o, lst2, k, h);
            }
            ir1 += s1; ir2 += s2; ro += s3;
        }

        // ---- U1: layer-1 update; output memo for step t-1 ----
        float r1 = (float)ir1 * IQSCALE;
        bb1v = ro1 * bb1v + BETAC * (1.f - ro1) * spk1;
        mem1 = mem1 * alpha1 - bb1v * spk1 + (1.f - alpha1) * (xp_cur + r1);
        float ns1 = (mem1 - bb1v - BJ0) > 0.f ? 1.f : 0.f;
        spk1 = ns1;
        unsigned long long m1 = __ballot(ns1 != 0.f ? 1 : 0);
        if (lane == 0) wmask[wv] = m1;
        if (doo) {
            memo = memo * alpo + (1.f - alpo) * (bov + ro);
            smo[h] = memo;
        }
        __syncthreads();                               // B1

        // ---- P2b: rebuild flat lst1 (+pad to 32-mult); softmax for t-1 ----
        {
            int pos = __popcll(m1 & ((1ull << lane) - 1ull));
            int tot = 0;
            for (int w = 0; w < 4; ++w) {
                unsigned long long mw = wmask[w];
                if (w < wv) pos += __popcll(mw);
                tot += __popcll(mw);
            }
            if (ns1 != 0.f) lst1[pos] = h;
            int np = (tot + 31) & ~31;
            if (h < np - tot) lst1[tot + h] = DUMMY;
            n1p = np;
        }
        if (doo) {
            float mx = smo[0];
            for (int i = 1; i < DOUT; ++i) mx = fmaxf(mx, smo[i]);
            float s = 0.f;
            for (int i = 0; i < DOUT; ++i) s += expf(smo[i] - mx);
            accs += expf(memo - mx) / s;
        }
        __syncthreads();                               // B2

        // ---- P3: gather sT12 over fresh lst1 ----
        int ir3 = 0;
        for (int k = 0; k < n1p; k += 32) ir3 += gath32i(sT12, lst1, k, h);

        // ---- U2: layer-2 update ----
        float r23 = (float)(ir2 + ir3) * IQSCALE;
        bb2v = ro2 * bb2v + BETAC * (1.f - ro2) * spk2;
        mem2 = mem2 * alpha2 - bb2v * spk2 + (1.f - alpha2) * (bh2v + r23);
        float ns2 = (mem2 - bb2v - BJ0) > 0.f ? 1.f : 0.f;
        spk2 = ns2;
        unsigned long long m2 = __ballot(ns2 != 0.f ? 1 : 0);
        if (lane == 0) wmask[wv] = m2;
        __syncthreads();                               // B3

        // ---- P4b: rebuild flat lst2 (+pad to 32-mult) ----
        {
            int pos = __popcll(m2 & ((1ull << lane) - 1ull));
            int tot = 0;
            for (int w = 0; w < 4; ++w) {
                unsigned long long mw = wmask[w];
                if (w < wv) pos += __popcll(mw);
                tot += __popcll(mw);
            }
            if (ns2 != 0.f) lst2[pos] = h;
            int np = (tot + 31) & ~31;
            if (h < np - tot) lst2[tot + h] = DUMMY;
            n2p = np;
        }
        __syncthreads();                               // B4

        xp_cur = xp_nxt;
    }

    // ---- Epilogue: output + softmax for the final timestep ----
    if (h < DOUT) {
        float ro = 0.f;
        for (int k = 0; k < n2p; k += 32) ro += gather32o(wT2o, lst2, k, h);
        memo = memo * alpo + (1.f - alpo) * (bov + ro);
        smo[h] = memo;
    }
    __syncthreads();
    if (h < DOUT) {
        float mx = smo[0];
        for (int i = 1; i < DOUT; ++i) mx = fmaxf(mx, smo[i]);
        float s = 0.f;
        for (int i = 0; i < DOUT; ++i) s += expf(smo[i] - mx);
        accs += expf(memo - mx) / s;
        out[b * DOUT + h] = accs;
    }
}

extern "C" void kernel_launch(void* const* d_in, const int* in_sizes, int n_in,
                              void* d_out, int out_size, void* d_ws, size_t ws_size,
                              hipStream_t stream) {
    const float* x          = (const float*)d_in[0];
    const float* w_i2h1     = (const float*)d_in[1];
    const float* w_h12h1    = (const float*)d_in[2];
    const float* w_h12h2    = (const float*)d_in[3];
    const float* w_h22h2    = (const float*)d_in[4];
    const float* w_h2o      = (const float*)d_in[5];
    const float* b_h1       = (const float*)d_in[6];
    const float* b_h2       = (const float*)d_in[7];
    const float* b_o        = (const float*)d_in[8];
    const float* tau_adp_h1 = (const float*)d_in[9];
    const float* tau_adp_h2 = (const float*)d_in[10];
    const float* tau_m_h1   = (const float*)d_in[11];
    const float* tau_m_h2   = (const float*)d_in[12];
    const float* tau_m_o    = (const float*)d_in[13];

    short* sws = (short*)d_ws;
    float* fws = (float*)d_ws;
    const short* sT1  = sws;
    const short* sT11 = sws + SOFF_T11;
    const short* sT12 = sws + SOFF_T12;
    const short* sT22 = sws + SOFF_T22;
    float* wT2o = fws + FOFF_W2O;
    float* Xp   = fws + FOFF_XP;

    transpose_all_k<<<(N_TRANS + 255) / 256, 256, 0, stream>>>(
        w_i2h1, w_h12h1, w_h12h2, w_h22h2, w_h2o, sws, fws);

    xproj_k<<<(TT * BB) / 4, 256, 0, stream>>>(x, sT1, b_h1, Xp);

    rec_k<<<BB, 256, 0, stream>>>(Xp, sT11, sT12, sT22, wT2o,
                                  b_h2, b_o, tau_adp_h1, tau_adp_h2,
                                  tau_m_h1, tau_m_h2, tau_m_o,
                                  (float*)d_out);
}

// Round 11
// 1058.719 us; speedup vs baseline: 1.3311x; 1.2213x over previous
//
#include <hip/hip_runtime.h>
#include <cstdint>
#include <cstddef>

#define BB 256
#define TT 250
#define DIN 700
#define H1 256
#define H2 256
#define DOUT 20
#define BJ0 0.01f
#define BETAC 1.8f
#define DUMMY 256                 // zero row index in every padded table
#define IQSCALE 3.814697265625e-06f   // 2^-18

typedef float f32x4 __attribute__((ext_vector_type(4)));
typedef short s16x4 __attribute__((ext_vector_type(4)));

// ---------------------------------------------------------------------------
// Workspace layout. int16 tables (element offsets in shorts from ws base):
//   sT1  [701*256] @ 0        (row 700 = zeros)
//   sT11 [257*256] @ 179456   (row 256 = zeros)
//   sT12 [257*256] @ 245248
//   sT22 [257*256] @ 311040   (end: 376832 shorts = 753664 bytes)
// fp32 region (float offsets from ws base):
//   wT2o [257*20]  @ f188416  (row 256 = zeros)
//   Xp   [250*256*256] @ f193556  (byte 774224, 16B aligned)
// ---------------------------------------------------------------------------
#define SOFF_T11 179456
#define SOFF_T12 245248
#define SOFF_T22 311040
#define FOFF_W2O 188416
#define FOFF_XP  193556
#define N_TRANS  381972

__device__ __forceinline__ short q18(float w) {
    float s = w * 262144.0f;
    s = fminf(fmaxf(s, -32767.0f), 32767.0f);
    return (short)__float2int_rn(s);
}

__global__ void transpose_all_k(const float* __restrict__ w_i2h1,
                                const float* __restrict__ w_h12h1,
                                const float* __restrict__ w_h12h2,
                                const float* __restrict__ w_h22h2,
                                const float* __restrict__ w_h2o,
                                short* __restrict__ sws,
                                float* __restrict__ fws) {
    int i = blockIdx.x * blockDim.x + threadIdx.x;
    if (i < 179456) { int d = i >> 8, h = i & 255;
        sws[i] = q18((d < DIN) ? w_i2h1[h * DIN + d] : 0.f); return; }
    i -= 179456;
    if (i < 65792) { int d = i >> 8, h = i & 255;
        sws[SOFF_T11 + i] = q18((d < H1) ? w_h12h1[h * H1 + d] : 0.f); return; }
    i -= 65792;
    if (i < 65792) { int d = i >> 8, h = i & 255;
        sws[SOFF_T12 + i] = q18((d < H1) ? w_h12h2[h * H1 + d] : 0.f); return; }
    i -= 65792;
    if (i < 65792) { int d = i >> 8, h = i & 255;
        sws[SOFF_T22 + i] = q18((d < H2) ? w_h22h2[h * H2 + d] : 0.f); return; }
    i -= 65792;
    if (i < 5140)  { int j = i / 20, h = i % 20;
        fws[FOFF_W2O + i] = (j < H2) ? w_h2o[h * H2 + j] : 0.f; return; }
}

// ---------------------------------------------------------------------------
// Xp[t][b][h] = b_h1[h] + (Σ_{d active} sT1[d*256+h]) * 2^-18   (R8 verbatim)
// ---------------------------------------------------------------------------
__global__ __launch_bounds__(256) void xproj_k(const float* __restrict__ x,
                                               const short* __restrict__ sT1,
                                               const float* __restrict__ b_h1,
                                               float* __restrict__ Xp) {
    const int lane = threadIdx.x & 63;
    const int wv   = threadIdx.x >> 6;
    const int bt   = blockIdx.x * 4 + wv;   // grid = T*B/4 = 16000
    const int b    = bt & (BB - 1);
    const int t    = bt >> 8;

    __shared__ __align__(16) int lst[4][712];

    const float* xrow = x + ((size_t)b * TT + t) * DIN;
    int cnt = 0;
    for (int c = 0; c < 11; ++c) {
        int d = c * 64 + lane;
        bool p = false;
        if (d < DIN) p = (__builtin_nontemporal_load(xrow + d) != 0.0f);
        unsigned long long m = __ballot(p ? 1 : 0);
        if (p) {
            int pos = cnt + __popcll(m & ((1ull << lane) - 1ull));
            lst[wv][pos] = d;
        }
        cnt += __popcll(m);
    }
    int cntp = (cnt + 7) & ~7;
    if (lane < cntp - cnt) lst[wv][cnt + lane] = DIN;   // zero row pad
    __syncthreads();

    const int lo = lane * 4;
    int i0 = 0, i1 = 0, i2 = 0, i3 = 0;
    int j0 = 0, j1 = 0, j2 = 0, j3 = 0;
    for (int k = 0; k < cntp; k += 8) {
        int4 ja = *(const int4*)&lst[wv][k];
        int4 jb = *(const int4*)&lst[wv][k + 4];
        s16x4 w0 = *(const s16x4*)(sT1 + ((size_t)ja.x << 8) + lo);
        s16x4 w1 = *(const s16x4*)(sT1 + ((size_t)ja.y << 8) + lo);
        s16x4 w2 = *(const s16x4*)(sT1 + ((size_t)ja.z << 8) + lo);
        s16x4 w3 = *(const s16x4*)(sT1 + ((size_t)ja.w << 8) + lo);
        s16x4 w4 = *(const s16x4*)(sT1 + ((size_t)jb.x << 8) + lo);
        s16x4 w5 = *(const s16x4*)(sT1 + ((size_t)jb.y << 8) + lo);
        s16x4 w6 = *(const s16x4*)(sT1 + ((size_t)jb.z << 8) + lo);
        s16x4 w7 = *(const s16x4*)(sT1 + ((size_t)jb.w << 8) + lo);
        i0 += (w0.x + w1.x) + (w2.x + w3.x);  j0 += (w4.x + w5.x) + (w6.x + w7.x);
        i1 += (w0.y + w1.y) + (w2.y + w3.y);  j1 += (w4.y + w5.y) + (w6.y + w7.y);
        i2 += (w0.z + w1.z) + (w2.z + w3.z);  j2 += (w4.z + w5.z) + (w6.z + w7.z);
        i3 += (w0.w + w1.w) + (w2.w + w3.w);  j3 += (w4.w + w5.w) + (w6.w + w7.w);
    }
    f32x4 acc = *(const f32x4*)(b_h1 + lo);
    acc.x += (float)(i0 + j0) * IQSCALE;
    acc.y += (float)(i1 + j1) * IQSCALE;
    acc.z += (float)(i2 + j2) * IQSCALE;
    acc.w += (float)(i3 + j3) * IQSCALE;
    __builtin_nontemporal_store(acc, (f32x4*)(Xp + ((size_t)t * BB + b) * H1 + lo));
}

// Dual-table gather: 16 rows from L[k..k+16), SAME offsets into W1 and W2
// (W2 = W1 shifted base) -> one address calc feeds two loads.
__device__ __forceinline__ void gath16d(const short* __restrict__ W1,
                                        const short* __restrict__ W2,
                                        const int* __restrict__ L, int k, int h,
                                        int& r1, int& r2) {
    int4 a = *(const int4*)(L + k);
    int4 b = *(const int4*)(L + k + 4);
    int4 c = *(const int4*)(L + k + 8);
    int4 d = *(const int4*)(L + k + 12);
    int o0  = (a.x << 8) + h, o1  = (a.y << 8) + h, o2  = (a.z << 8) + h, o3  = (a.w << 8) + h;
    int o4  = (b.x << 8) + h, o5  = (b.y << 8) + h, o6  = (b.z << 8) + h, o7  = (b.w << 8) + h;
    int o8  = (c.x << 8) + h, o9  = (c.y << 8) + h, o10 = (c.z << 8) + h, o11 = (c.w << 8) + h;
    int o12 = (d.x << 8) + h, o13 = (d.y << 8) + h, o14 = (d.z << 8) + h, o15 = (d.w << 8) + h;
    int u0 = W1[o0], u1 = W1[o1], u2  = W1[o2],  u3  = W1[o3];
    int u4 = W1[o4], u5 = W1[o5], u6  = W1[o6],  u7  = W1[o7];
    int u8 = W1[o8], u9 = W1[o9], u10 = W1[o10], u11 = W1[o11];
    int u12 = W1[o12], u13 = W1[o13], u14 = W1[o14], u15 = W1[o15];
    int v0 = W2[o0], v1 = W2[o1], v2  = W2[o2],  v3  = W2[o3];
    int v4 = W2[o4], v5 = W2[o5], v6  = W2[o6],  v7  = W2[o7];
    int v8 = W2[o8], v9 = W2[o9], v10 = W2[o10], v11 = W2[o11];
    int v12 = W2[o12], v13 = W2[o13], v14 = W2[o14], v15 = W2[o15];
    r1 += (((u0 + u1) + (u2 + u3)) + ((u4 + u5) + (u6 + u7)))
        + (((u8 + u9) + (u10 + u11)) + ((u12 + u13) + (u14 + u15)));
    r2 += (((v0 + v1) + (v2 + v3)) + ((v4 + v5) + (v6 + v7)))
        + (((v8 + v9) + (v10 + v11)) + ((v12 + v13) + (v14 + v15)));
}

// 16 gathered int16 adds (single table) — R8 verbatim.
__device__ __forceinline__ int gath16i(const short* __restrict__ W,
                                       const int* __restrict__ L, int k, int h) {
    int4 a = *(const int4*)(L + k);
    int4 b = *(const int4*)(L + k + 4);
    int4 c = *(const int4*)(L + k + 8);
    int4 d = *(const int4*)(L + k + 12);
    int v0  = W[(a.x << 8) + h], v1  = W[(a.y << 8) + h];
    int v2  = W[(a.z << 8) + h], v3  = W[(a.w << 8) + h];
    int v4  = W[(b.x << 8) + h], v5  = W[(b.y << 8) + h];
    int v6  = W[(b.z << 8) + h], v7  = W[(b.w << 8) + h];
    int v8  = W[(c.x << 8) + h], v9  = W[(c.y << 8) + h];
    int v10 = W[(c.z << 8) + h], v11 = W[(c.w << 8) + h];
    int v12 = W[(d.x << 8) + h], v13 = W[(d.y << 8) + h];
    int v14 = W[(d.z << 8) + h], v15 = W[(d.w << 8) + h];
    return (((v0 + v1) + (v2 + v3)) + ((v4 + v5) + (v6 + v7)))
         + (((v8 + v9) + (v10 + v11)) + ((v12 + v13) + (v14 + v15)));
}

// 16 fp32 output-weight values, stride-20 table — R8 verbatim.
__device__ __forceinline__ float gather16o(const float* __restrict__ W,
                                           const int* __restrict__ L, int k, int h) {
    int4 a = *(const int4*)(L + k);
    int4 b = *(const int4*)(L + k + 4);
    int4 c = *(const int4*)(L + k + 8);
    int4 d = *(const int4*)(L + k + 12);
    float v0  = W[a.x * DOUT + h], v1  = W[a.y * DOUT + h];
    float v2  = W[a.z * DOUT + h], v3  = W[a.w * DOUT + h];
    float v4  = W[b.x * DOUT + h], v5  = W[b.y * DOUT + h];
    float v6  = W[b.z * DOUT + h], v7  = W[b.w * DOUT + h];
    float v8  = W[c.x * DOUT + h], v9  = W[c.y * DOUT + h];
    float v10 = W[c.z * DOUT + h], v11 = W[c.w * DOUT + h];
    float v12 = W[d.x * DOUT + h], v13 = W[d.y * DOUT + h];
    float v14 = W[d.z * DOUT + h], v15 = W[d.w * DOUT + h];
    return (((v0 + v1) + (v2 + v3)) + ((v4 + v5) + (v6 + v7)))
         + (((v8 + v9) + (v10 + v11)) + ((v12 + v13) + (v14 + v15)));
}

// ---------------------------------------------------------------------------
// rec_k: LAYER-PIPELINED recurrent loop. Iteration i computes U1(step i) and
// U2(step i-1); output-neuron/softmax for step i-2. Consequence: ALL gathers
// (wT11 & wT12 over lst1=spk1(i-1); wT22 & wT2o over lst2=spk2(i-2)) depend
// only on previous-iteration lists -> ONE fused drain chain, 2 barriers/step,
// shared address math for wT11/wT12. Thread h = neuron h throughout; list
// build identical to R8. i runs 0..TT+1 with uniform guards.
// ---------------------------------------------------------------------------
__global__ __launch_bounds__(256) void rec_k(
    const float* __restrict__ Xp,
    const short* __restrict__ sT11, const short* __restrict__ sT12,
    const short* __restrict__ sT22, const float* __restrict__ wT2o,
    const float* __restrict__ b_h2, const float* __restrict__ b_o,
    const float* __restrict__ tau_adp_h1, const float* __restrict__ tau_adp_h2,
    const float* __restrict__ tau_m_h1, const float* __restrict__ tau_m_h2,
    const float* __restrict__ tau_m_o,
    float* __restrict__ out) {
    const int h    = threadIdx.x;
    const int lane = h & 63;
    const int wv   = h >> 6;
    const int b    = blockIdx.x;

    __shared__ __align__(16) int lst1[272];
    __shared__ __align__(16) int lst2[272];
    __shared__ unsigned long long wm1[4];
    __shared__ unsigned long long wm2[4];
    __shared__ float smo[DOUT];

    const float alpha1 = expf(-1.0f / tau_m_h1[h]);
    const float ro1    = expf(-1.0f / tau_adp_h1[h]);
    const float alpha2 = expf(-1.0f / tau_m_h2[h]);
    const float ro2    = expf(-1.0f / tau_adp_h2[h]);
    const float bh2v   = b_h2[h];
    float alpo = 0.f, bov = 0.f;
    if (h < DOUT) { alpo = expf(-1.0f / tau_m_o[h]); bov = b_o[h]; }

    float mem1 = 0.f, spk1 = 0.f, bb1v = BJ0;
    float mem2 = 0.f, spk2 = 0.f, bb2v = BJ0;
    float memo = 0.f, accs = 0.f;
    int n1p = 0, n2p = 0;

    float xp_cur = __builtin_nontemporal_load(Xp + ((size_t)b) * H1 + h);  // step 0

    for (int i = 0; i <= TT + 1; ++i) {
        float xp_nxt = 0.f;
        if (i + 1 < TT)
            xp_nxt = __builtin_nontemporal_load(Xp + ((size_t)(i + 1) * BB + b) * H1 + h);

        // ---- G: ONE fused gather chain over lst1 (spk1(i-1)) + lst2 (spk2(i-2))
        int ir11 = 0, ir12 = 0, ir22 = 0;
        float ro = 0.f;
        const bool dmo = (h < DOUT) && (i >= 2);     // output/softmax this iter
        const int kmax = n1p > n2p ? n1p : n2p;
        for (int k = 0; k < kmax; k += 16) {
            if (k < n1p) gath16d(sT11, sT12, lst1, k, h, ir11, ir12);
            if (k < n2p) {
                ir22 += gath16i(sT22, lst2, k, h);
                if (dmo) ro += gather16o(wT2o, lst2, k, h);
            }
        }

        // ---- U1(step i) ----
        unsigned long long m1 = 0, m2 = 0;
        float ns1 = 0.f, ns2 = 0.f;
        if (i < TT) {
            float r1 = (float)ir11 * IQSCALE;
            bb1v = ro1 * bb1v + BETAC * (1.f - ro1) * spk1;
            mem1 = mem1 * alpha1 - bb1v * spk1 + (1.f - alpha1) * (xp_cur + r1);
            ns1 = (mem1 - bb1v - BJ0) > 0.f ? 1.f : 0.f;
            spk1 = ns1;
            m1 = __ballot(ns1 != 0.f ? 1 : 0);
            if (lane == 0) wm1[wv] = m1;
        }
        // ---- U2(step i-1) ----
        if (i >= 1 && i <= TT) {
            float r23 = (float)(ir22 + ir12) * IQSCALE;
            bb2v = ro2 * bb2v + BETAC * (1.f - ro2) * spk2;
            mem2 = mem2 * alpha2 - bb2v * spk2 + (1.f - alpha2) * (bh2v + r23);
            ns2 = (mem2 - bb2v - BJ0) > 0.f ? 1.f : 0.f;
            spk2 = ns2;
            m2 = __ballot(ns2 != 0.f ? 1 : 0);
            if (lane == 0) wm2[wv] = m2;
        }
        // ---- output neuron memo(step i-2) ----
        if (dmo) {
            memo = memo * alpo + (1.f - alpo) * (bov + ro);
            smo[h] = memo;
        }
        __syncthreads();                             // B1: list reads done; wm/smo visible

        // ---- rebuild lst1 <- spk1(i) ----
        if (i < TT) {
            int pos = __popcll(m1 & ((1ull << lane) - 1ull));
            int tot = 0;
            for (int w = 0; w < 4; ++w) {
                unsigned long long mw = wm1[w];
                if (w < wv) pos += __popcll(mw);
                tot += __popcll(mw);
            }
            if (ns1 != 0.f) lst1[pos] = h;
            int np = (tot + 15) & ~15;
            if (h < np - tot) lst1[tot + h] = DUMMY;
            n1p = np;
        } else {
            n1p = 0;
        }
        // ---- rebuild lst2 <- spk2(i-1) ----
        if (i >= 1 && i <= TT) {
            int pos = __popcll(m2 & ((1ull << lane) - 1ull));
            int tot = 0;
            for (int w = 0; w < 4; ++w) {
                unsigned long long mw = wm2[w];
                if (w < wv) pos += __popcll(mw);
                tot += __popcll(mw);
            }
            if (ns2 != 0.f) lst2[pos] = h;
            int np = (tot + 15) & ~15;
            if (h < np - tot) lst2[tot + h] = DUMMY;
            n2p = np;
        }
        // ---- softmax accum for step i-2 ----
        if (dmo) {
            float mx = smo[0];
            for (int j = 1; j < DOUT; ++j) mx = fmaxf(mx, smo[j]);
            float s = 0.f;
            for (int j = 0; j < DOUT; ++j) s += expf(smo[j] - mx);
            accs += expf(memo - mx) / s;
        }
        __syncthreads();                             // B2: lists ready

        xp_cur = xp_nxt;
    }

    if (h < DOUT) out[b * DOUT + h] = accs;
}

extern "C" void kernel_launch(void* const* d_in, const int* in_sizes, int n_in,
                              void* d_out, int out_size, void* d_ws, size_t ws_size,
                              hipStream_t stream) {
    const float* x          = (const float*)d_in[0];
    const float* w_i2h1     = (const float*)d_in[1];
    const float* w_h12h1    = (const float*)d_in[2];
    const float* w_h12h2    = (const float*)d_in[3];
    const float* w_h22h2    = (const float*)d_in[4];
    const float* w_h2o      = (const float*)d_in[5];
    const float* b_h1       = (const float*)d_in[6];
    const float* b_h2       = (const float*)d_in[7];
    const float* b_o        = (const float*)d_in[8];
    const float* tau_adp_h1 = (const float*)d_in[9];
    const float* tau_adp_h2 = (const float*)d_in[10];
    const float* tau_m_h1   = (const float*)d_in[11];
    const float* tau_m_h2   = (const float*)d_in[12];
    const float* tau_m_o    = (const float*)d_in[13];

    short* sws = (short*)d_ws;
    float* fws = (float*)d_ws;
    const short* sT1  = sws;
    const short* sT11 = sws + SOFF_T11;
    const short* sT12 = sws + SOFF_T12;
    const short* sT22 = sws + SOFF_T22;
    float* wT2o = fws + FOFF_W2O;
    float* Xp   = fws + FOFF_XP;

    transpose_all_k<<<(N_TRANS + 255) / 256, 256, 0, stream>>>(
        w_i2h1, w_h12h1, w_h12h2, w_h22h2, w_h2o, sws, fws);

    xproj_k<<<(TT * BB) / 4, 256, 0, stream>>>(x, sT1, b_h1, Xp);

    rec_k<<<BB, 256, 0, stream>>>(Xp, sT11, sT12, sT22, wT2o,
                                  b_h2, b_o, tau_adp_h1, tau_adp_h2,
                                  tau_m_h1, tau_m_h2, tau_m_o,
                                  (float*)d_out);
}